// Round 3
// baseline (450.065 us; speedup 1.0000x reference)
//
#include <hip/hip_runtime.h>

// TriangleAttentionStartingNode  (B=1, S=256, C=128, H=4, D=32)
//
// Pipeline:
//   K1 ln_kernel:   z (65536x128) -> zn                       [ws slot 0]
//   K2 proj_kernel: zn @ {wq,wk,wv,wg} -> qt,kt,vt (layout [j*4+h][row][32]), g (row-major)
//   K3 attn_kernel: per (j,h): softmax(q k^T * scale) v, gated by g -> go  [reuses ws slot 0]
//   K4 out_kernel:  go @ wo -> d_out
//
// wb is skipped: bias b[i,j,h] broadcasts over the softmax axis k, and
// softmax(x + c) == softmax(x), so it cancels exactly.
//
// All math fp32 (threshold 1e-2 absolute; bf16 paths deferred to later rounds).
// ws usage: 5 * 65536*128 floats = 167.8 MB.

#define NROWS 65536   // S*S

// ---------------------------------------------------------------- K1: LayerNorm
__global__ __launch_bounds__(256) void ln_kernel(const float* __restrict__ z,
                                                 const float* __restrict__ w,
                                                 const float* __restrict__ b,
                                                 float* __restrict__ zn)
{
    const int row  = blockIdx.x * 4 + (threadIdx.x >> 6);   // one wave per row
    const int lane = threadIdx.x & 63;
    const float2 v = *(const float2*)(z + (size_t)row * 128 + lane * 2);
    float s  = v.x + v.y;
    float ss = v.x * v.x + v.y * v.y;
    #pragma unroll
    for (int off = 32; off > 0; off >>= 1) {
        s  += __shfl_xor(s,  off);
        ss += __shfl_xor(ss, off);
    }
    const float mu  = s * (1.0f / 128.0f);
    const float var = ss * (1.0f / 128.0f) - mu * mu;
    const float rs  = rsqrtf(var + 1e-5f);
    const int c = lane * 2;
    float2 o;
    o.x = (v.x - mu) * rs * w[c]     + b[c];
    o.y = (v.y - mu) * rs * w[c + 1] + b[c + 1];
    *(float2*)(zn + (size_t)row * 128 + c) = o;
}

// ------------------------------------------------- K2: fused projection GEMM
// C[65536 x 512] = zn[65536 x 128] @ [wq|wk|wv|wg], blockIdx.y selects matrix.
// 128x128 block tile, 256 threads, 8x8 register tile, K-chunks of 32.
__global__ __launch_bounds__(256) void proj_kernel(const float* __restrict__ zn,
                                                   const float* __restrict__ wq,
                                                   const float* __restrict__ wk,
                                                   const float* __restrict__ wv,
                                                   const float* __restrict__ wg,
                                                   float* __restrict__ qt,
                                                   float* __restrict__ kt,
                                                   float* __restrict__ vt,
                                                   float* __restrict__ gb)
{
    const int by   = blockIdx.x;          // 0..511
    const int bx   = blockIdx.y;          // 0..3 : q,k,v,g
    const int row0 = by * 128;
    const float* __restrict__ W = (bx == 0) ? wq : (bx == 1) ? wk : (bx == 2) ? wv : wg;

    __shared__ float As[32][132];   // A transposed: As[k][m], pad->stride 132 (16B aligned rows)
    __shared__ float Bs[32][132];   // Bs[k][n]

    const int tid = threadIdx.x;
    const int tm  = tid & 15, tn = tid >> 4;
    const int m0  = tm * 4,  n0 = tn * 4;

    float acc[8][8];
    #pragma unroll
    for (int a = 0; a < 8; ++a)
        #pragma unroll
        for (int q = 0; q < 8; ++q) acc[a][q] = 0.0f;

    for (int kc = 0; kc < 128; kc += 32) {
        __syncthreads();
        // A tile: 128 rows x 32 cols, coalesced global (8 lanes/row), transposed into LDS
        #pragma unroll
        for (int it = 0; it < 4; ++it) {
            const int id = it * 256 + tid;
            const int m  = id >> 3;
            const int kq = (id & 7) * 4;
            const float4 a4 = *(const float4*)(zn + (size_t)(row0 + m) * 128 + kc + kq);
            As[kq + 0][m] = a4.x; As[kq + 1][m] = a4.y;
            As[kq + 2][m] = a4.z; As[kq + 3][m] = a4.w;
        }
        // B tile: rows kc..kc+31 of W (direct copy)
        #pragma unroll
        for (int it = 0; it < 4; ++it) {
            const int id = it * 256 + tid;
            const int kk = id >> 5;
            const int c4 = (id & 31) * 4;
            *(float4*)&Bs[kk][c4] = *(const float4*)(W + (size_t)(kc + kk) * 128 + c4);
        }
        __syncthreads();
        #pragma unroll
        for (int k = 0; k < 32; ++k) {
            const float4 a0 = *(const float4*)&As[k][m0];
            const float4 a1 = *(const float4*)&As[k][m0 + 64];
            const float4 b0 = *(const float4*)&Bs[k][n0];
            const float4 b1 = *(const float4*)&Bs[k][n0 + 64];
            const float av[8] = {a0.x, a0.y, a0.z, a0.w, a1.x, a1.y, a1.z, a1.w};
            const float bv[8] = {b0.x, b0.y, b0.z, b0.w, b1.x, b1.y, b1.z, b1.w};
            #pragma unroll
            for (int ii = 0; ii < 8; ++ii)
                #pragma unroll
                for (int jj = 0; jj < 8; ++jj)
                    acc[ii][jj] += av[ii] * bv[jj];
        }
    }

    // Epilogue: scatter into attention-friendly layouts.
    #pragma unroll
    for (int ii = 0; ii < 8; ++ii) {
        const int mA = (ii < 4) ? (m0 + ii) : (m0 + 60 + ii);   // ii=4 -> m0+64
        const int r  = row0 + mA;
        #pragma unroll
        for (int nh = 0; nh < 2; ++nh) {
            const int c0 = n0 + nh * 64;
            float4 vv;
            vv.x = acc[ii][nh * 4 + 0]; vv.y = acc[ii][nh * 4 + 1];
            vv.z = acc[ii][nh * 4 + 2]; vv.w = acc[ii][nh * 4 + 3];
            if (bx == 3) {
                vv.x = 1.0f / (1.0f + __expf(-vv.x));
                vv.y = 1.0f / (1.0f + __expf(-vv.y));
                vv.z = 1.0f / (1.0f + __expf(-vv.z));
                vv.w = 1.0f / (1.0f + __expf(-vv.w));
                *(float4*)(gb + (size_t)r * 128 + c0) = vv;
            } else {
                const int h = c0 >> 5, d0 = c0 & 31;
                if (bx == 0) {
                    // q at zn row r=(i,j): i=r>>8, j=r&255 -> qt[(j*4+h)][i][d]
                    const int i = r >> 8, j = r & 255;
                    *(float4*)(qt + (size_t)(j * 4 + h) * 8192 + i * 32 + d0) = vv;
                } else {
                    // k/v at zn row r=(j,kk): j=r>>8 -> kt[(j*4+h)][kk][d]
                    const int j = r >> 8, kk2 = r & 255;
                    float* dst = (bx == 1) ? kt : vt;
                    *(float4*)(dst + (size_t)(j * 4 + h) * 8192 + kk2 * 32 + d0) = vv;
                }
            }
        }
    }
}

// ---------------------------------------------------------- K3: attention
// One block per (j,h) = 1024 blocks; one thread per query row i (256 threads).
// K/V rows are wave-uniform loads (L2 broadcast) -> pure-VALU inner loop.
__global__ __launch_bounds__(256) void attn_kernel(const float* __restrict__ qt,
                                                   const float* __restrict__ kt,
                                                   const float* __restrict__ vt,
                                                   const float* __restrict__ gb,
                                                   float* __restrict__ go)
{
    const int jh = blockIdx.x;
    const int j = jh >> 2, h = jh & 3;
    const int i = threadIdx.x;
    const float* __restrict__ Kp = kt + (size_t)jh * 8192;
    const float* __restrict__ Vp = vt + (size_t)jh * 8192;
    const float* __restrict__ Qp = qt + (size_t)jh * 8192 + i * 32;

    float q[32];
    #pragma unroll
    for (int dq = 0; dq < 8; ++dq) {
        const float4 t = *(const float4*)(Qp + dq * 4);
        q[dq * 4 + 0] = t.x; q[dq * 4 + 1] = t.y;
        q[dq * 4 + 2] = t.z; q[dq * 4 + 3] = t.w;
    }

    const float scale = 0.17677669529663687f;   // 1/sqrt(32)
    float m = -1e30f, l = 0.0f;
    float o[32];
    #pragma unroll
    for (int d = 0; d < 32; ++d) o[d] = 0.0f;

    for (int k = 0; k < 256; ++k) {
        float s = 0.0f;
        #pragma unroll
        for (int dq = 0; dq < 8; ++dq) {
            const float4 kr = *(const float4*)(Kp + k * 32 + dq * 4);
            s += q[dq * 4 + 0] * kr.x + q[dq * 4 + 1] * kr.y
               + q[dq * 4 + 2] * kr.z + q[dq * 4 + 3] * kr.w;
        }
        s *= scale;
        // (bias b[i,j,h] omitted: constant along k, cancels in softmax)
        if (s > m) {            // defer-rescale online softmax
            const float corr = __expf(m - s);
            l *= corr;
            #pragma unroll
            for (int d = 0; d < 32; ++d) o[d] *= corr;
            m = s;
        }
        const float p = __expf(s - m);
        l += p;
        #pragma unroll
        for (int dq = 0; dq < 8; ++dq) {
            const float4 vr = *(const float4*)(Vp + k * 32 + dq * 4);
            o[dq * 4 + 0] += p * vr.x; o[dq * 4 + 1] += p * vr.y;
            o[dq * 4 + 2] += p * vr.z; o[dq * 4 + 3] += p * vr.w;
        }
    }

    const float inv = 1.0f / l;
    const size_t r = (size_t)i * 256 + j;       // output position (i,j)
    const float* gp = gb + r * 128 + h * 32;
    float*       op = go + r * 128 + h * 32;
    #pragma unroll
    for (int dq = 0; dq < 8; ++dq) {
        const float4 gv = *(const float4*)(gp + dq * 4);
        float4 ov;
        ov.x = gv.x * o[dq * 4 + 0] * inv;
        ov.y = gv.y * o[dq * 4 + 1] * inv;
        ov.z = gv.z * o[dq * 4 + 2] * inv;
        ov.w = gv.w * o[dq * 4 + 3] * inv;
        *(float4*)(op + dq * 4) = ov;
    }
}

// ------------------------------------------------------- K4: output GEMM
// out[65536 x 128] = go @ wo   (same tiling as proj_kernel, plain store)
__global__ __launch_bounds__(256) void out_kernel(const float* __restrict__ A,
                                                  const float* __restrict__ W,
                                                  float* __restrict__ out)
{
    const int by   = blockIdx.x;
    const int row0 = by * 128;

    __shared__ float As[32][132];
    __shared__ float Bs[32][132];

    const int tid = threadIdx.x;
    const int tm  = tid & 15, tn = tid >> 4;
    const int m0  = tm * 4,  n0 = tn * 4;

    float acc[8][8];
    #pragma unroll
    for (int a = 0; a < 8; ++a)
        #pragma unroll
        for (int q = 0; q < 8; ++q) acc[a][q] = 0.0f;

    for (int kc = 0; kc < 128; kc += 32) {
        __syncthreads();
        #pragma unroll
        for (int it = 0; it < 4; ++it) {
            const int id = it * 256 + tid;
            const int m  = id >> 3;
            const int kq = (id & 7) * 4;
            const float4 a4 = *(const float4*)(A + (size_t)(row0 + m) * 128 + kc + kq);
            As[kq + 0][m] = a4.x; As[kq + 1][m] = a4.y;
            As[kq + 2][m] = a4.z; As[kq + 3][m] = a4.w;
        }
        #pragma unroll
        for (int it = 0; it < 4; ++it) {
            const int id = it * 256 + tid;
            const int kk = id >> 5;
            const int c4 = (id & 31) * 4;
            *(float4*)&Bs[kk][c4] = *(const float4*)(W + (size_t)(kc + kk) * 128 + c4);
        }
        __syncthreads();
        #pragma unroll
        for (int k = 0; k < 32; ++k) {
            const float4 a0 = *(const float4*)&As[k][m0];
            const float4 a1 = *(const float4*)&As[k][m0 + 64];
            const float4 b0 = *(const float4*)&Bs[k][n0];
            const float4 b1 = *(const float4*)&Bs[k][n0 + 64];
            const float av[8] = {a0.x, a0.y, a0.z, a0.w, a1.x, a1.y, a1.z, a1.w};
            const float bv[8] = {b0.x, b0.y, b0.z, b0.w, b1.x, b1.y, b1.z, b1.w};
            #pragma unroll
            for (int ii = 0; ii < 8; ++ii)
                #pragma unroll
                for (int jj = 0; jj < 8; ++jj)
                    acc[ii][jj] += av[ii] * bv[jj];
        }
    }

    #pragma unroll
    for (int ii = 0; ii < 8; ++ii) {
        const int mA = (ii < 4) ? (m0 + ii) : (m0 + 60 + ii);
        const int r  = row0 + mA;
        #pragma unroll
        for (int nh = 0; nh < 2; ++nh) {
            const int c0 = n0 + nh * 64;
            float4 vv;
            vv.x = acc[ii][nh * 4 + 0]; vv.y = acc[ii][nh * 4 + 1];
            vv.z = acc[ii][nh * 4 + 2]; vv.w = acc[ii][nh * 4 + 3];
            *(float4*)(out + (size_t)r * 128 + c0) = vv;
        }
    }
}

// ----------------------------------------------------------------- launch
extern "C" void kernel_launch(void* const* d_in, const int* in_sizes, int n_in,
                              void* d_out, int out_size, void* d_ws, size_t ws_size,
                              hipStream_t stream)
{
    const float* z   = (const float*)d_in[0];
    const float* lnw = (const float*)d_in[1];
    const float* lnb = (const float*)d_in[2];
    const float* wq  = (const float*)d_in[3];
    const float* wk  = (const float*)d_in[4];
    const float* wv  = (const float*)d_in[5];
    // d_in[6] = wb : unused (bias constant along softmax axis -> cancels)
    const float* wg  = (const float*)d_in[7];
    const float* wo  = (const float*)d_in[8];

    float* ws = (float*)d_ws;
    const size_t T = (size_t)NROWS * 128;       // 8,388,608 floats per tensor
    float* zn_go = ws;                          // zn, later reused for g*o
    float* qt    = ws + T;
    float* kt    = ws + 2 * T;
    float* vt    = ws + 3 * T;
    float* gb    = ws + 4 * T;                  // total 167.8 MB

    ln_kernel  <<<16384,          256, 0, stream>>>(z, lnw, lnb, zn_go);
    proj_kernel<<<dim3(512, 4),   256, 0, stream>>>(zn_go, wq, wk, wv, wg, qt, kt, vt, gb);
    attn_kernel<<<1024,           256, 0, stream>>>(qt, kt, vt, gb, zn_go);
    out_kernel <<<512,            256, 0, stream>>>(zn_go, wo, (float*)d_out);
}

// Round 4
// 280.822 us; speedup vs baseline: 1.6027x; 1.6027x over previous
//
#include <hip/hip_runtime.h>

// TriangleAttentionStartingNode  (B=1, S=256, C=128, H=4, D=32)
//
// Pipeline:
//   K1 ln_kernel:   z (65536x128) -> zn (fp32)
//   K2 proj_kernel: zn @ {wq,wk,wv,wg} ->
//        qt2: split-bf16 [jh][i][32hi|32lo]   (scale 1/sqrt(D) folded into q)
//        kt2: split-bf16 [jh][k][32hi|32lo]
//        vth/vtl: split-bf16 transposed [jh][d=32][k=256]
//        gb:  fp32 sigmoid gate, row-major [i][j][128]
//   K3 attn_kernel: MFMA split-bf16 flash attention per (j,h), swapped QK^T,
//        in-register softmax, bpermute P->A-frag relayout, gated write -> go
//   K4 out_kernel:  go @ wo -> d_out
//
// wb skipped: bias constant along softmax axis k -> cancels exactly.
// Split-bf16: x = hi + lo (both bf16); products keep hi*hi + hi*lo + lo*hi
// (error ~2^-18 relative) so accuracy stays ~fp32.

#define NROWS 65536   // S*S

typedef unsigned short u16;
typedef unsigned int   u32;
typedef __attribute__((ext_vector_type(8))) short short8;
typedef __attribute__((ext_vector_type(4))) float f32x4;
typedef __attribute__((ext_vector_type(4))) u32   u32x4;
typedef __attribute__((ext_vector_type(4))) u16   u16x4;

__device__ __forceinline__ u16 f2bf(float x) {            // fp32 -> bf16 RNE
    u32 u = __builtin_bit_cast(u32, x);
    return (u16)((u + 0x7fffu + ((u >> 16) & 1u)) >> 16);
}
__device__ __forceinline__ float bf2f(u16 h) {
    u32 u = (u32)h << 16;
    return __builtin_bit_cast(float, u);
}

// ---------------------------------------------------------------- K1: LayerNorm
__global__ __launch_bounds__(256) void ln_kernel(const float* __restrict__ z,
                                                 const float* __restrict__ w,
                                                 const float* __restrict__ b,
                                                 float* __restrict__ zn)
{
    const int row  = blockIdx.x * 4 + (threadIdx.x >> 6);   // one wave per row
    const int lane = threadIdx.x & 63;
    const float2 v = *(const float2*)(z + (size_t)row * 128 + lane * 2);
    float s  = v.x + v.y;
    float ss = v.x * v.x + v.y * v.y;
    #pragma unroll
    for (int off = 32; off > 0; off >>= 1) {
        s  += __shfl_xor(s,  off);
        ss += __shfl_xor(ss, off);
    }
    const float mu  = s * (1.0f / 128.0f);
    const float var = ss * (1.0f / 128.0f) - mu * mu;
    const float rs  = rsqrtf(var + 1e-5f);
    const int c = lane * 2;
    float2 o;
    o.x = (v.x - mu) * rs * w[c]     + b[c];
    o.y = (v.y - mu) * rs * w[c + 1] + b[c + 1];
    *(float2*)(zn + (size_t)row * 128 + c) = o;
}

// ------------------------------------------------- K2: fused projection GEMM
// 128x128 block tile, 256 threads, 8x8 register tile; epilogue splits to bf16.
__global__ __launch_bounds__(256) void proj_kernel(const float* __restrict__ zn,
                                                   const float* __restrict__ wq,
                                                   const float* __restrict__ wk,
                                                   const float* __restrict__ wv,
                                                   const float* __restrict__ wg,
                                                   u16* __restrict__ qt2,
                                                   u16* __restrict__ kt2,
                                                   u16* __restrict__ vth,
                                                   u16* __restrict__ vtl,
                                                   float* __restrict__ gb)
{
    const int by   = blockIdx.x;          // 0..511
    const int bx   = blockIdx.y;          // 0..3 : q,k,v,g
    const int row0 = by * 128;
    const float* __restrict__ W = (bx == 0) ? wq : (bx == 1) ? wk : (bx == 2) ? wv : wg;

    __shared__ float As[32][132];
    __shared__ float Bs[32][132];

    const int tid = threadIdx.x;
    const int tm  = tid & 15, tn = tid >> 4;
    const int m0  = tm * 4,  n0 = tn * 4;

    float acc[8][8];
    #pragma unroll
    for (int a = 0; a < 8; ++a)
        #pragma unroll
        for (int q = 0; q < 8; ++q) acc[a][q] = 0.0f;

    for (int kc = 0; kc < 128; kc += 32) {
        __syncthreads();
        #pragma unroll
        for (int it = 0; it < 4; ++it) {
            const int id = it * 256 + tid;
            const int m  = id >> 3;
            const int kq = (id & 7) * 4;
            const float4 a4 = *(const float4*)(zn + (size_t)(row0 + m) * 128 + kc + kq);
            As[kq + 0][m] = a4.x; As[kq + 1][m] = a4.y;
            As[kq + 2][m] = a4.z; As[kq + 3][m] = a4.w;
        }
        #pragma unroll
        for (int it = 0; it < 4; ++it) {
            const int id = it * 256 + tid;
            const int kk = id >> 5;
            const int c4 = (id & 31) * 4;
            *(float4*)&Bs[kk][c4] = *(const float4*)(W + (size_t)(kc + kk) * 128 + c4);
        }
        __syncthreads();
        #pragma unroll
        for (int k = 0; k < 32; ++k) {
            const float4 a0 = *(const float4*)&As[k][m0];
            const float4 a1 = *(const float4*)&As[k][m0 + 64];
            const float4 b0 = *(const float4*)&Bs[k][n0];
            const float4 b1 = *(const float4*)&Bs[k][n0 + 64];
            const float av[8] = {a0.x, a0.y, a0.z, a0.w, a1.x, a1.y, a1.z, a1.w};
            const float bv[8] = {b0.x, b0.y, b0.z, b0.w, b1.x, b1.y, b1.z, b1.w};
            #pragma unroll
            for (int ii = 0; ii < 8; ++ii)
                #pragma unroll
                for (int jj = 0; jj < 8; ++jj)
                    acc[ii][jj] += av[ii] * bv[jj];
        }
    }

    // Epilogue: split-bf16 scatter into attention layouts.
    #pragma unroll
    for (int ii = 0; ii < 8; ++ii) {
        const int mA = (ii < 4) ? (m0 + ii) : (m0 + 60 + ii);
        const int r  = row0 + mA;
        #pragma unroll
        for (int nh = 0; nh < 2; ++nh) {
            const int c0 = n0 + nh * 64;
            float vv[4] = {acc[ii][nh * 4 + 0], acc[ii][nh * 4 + 1],
                           acc[ii][nh * 4 + 2], acc[ii][nh * 4 + 3]};
            if (bx == 3) {
                float4 sg;
                sg.x = 1.0f / (1.0f + __expf(-vv[0]));
                sg.y = 1.0f / (1.0f + __expf(-vv[1]));
                sg.z = 1.0f / (1.0f + __expf(-vv[2]));
                sg.w = 1.0f / (1.0f + __expf(-vv[3]));
                *(float4*)(gb + (size_t)r * 128 + c0) = sg;
            } else {
                const int h  = c0 >> 5, d0 = c0 & 31;
                const int j  = (bx == 0) ? (r & 255) : (r >> 8);
                const int ot = (bx == 0) ? (r >> 8) : (r & 255);   // i or kk
                if (bx == 2) {
                    // V transposed: vth/vtl[(jh)*32 + d][kk]
                    #pragma unroll
                    for (int c = 0; c < 4; ++c) {
                        const float f = vv[c];
                        const u16 hx = f2bf(f);
                        const u16 lx = f2bf(f - bf2f(hx));
                        const size_t idx = ((size_t)(j * 4 + h) * 32 + d0 + c) * 256 + ot;
                        vth[idx] = hx; vtl[idx] = lx;
                    }
                } else {
                    u16* dst = ((bx == 0) ? qt2 : kt2) + ((size_t)(j * 4 + h) * 256 + ot) * 64;
                    const float sc = (bx == 0) ? 0.17677669529663687f : 1.0f; // 1/sqrt(32) into q
                    u16x4 hi, lo;
                    #pragma unroll
                    for (int c = 0; c < 4; ++c) {
                        const float f  = vv[c] * sc;
                        const u16  hx = f2bf(f);
                        hi[c] = hx;
                        lo[c] = f2bf(f - bf2f(hx));
                    }
                    *(u16x4*)(dst + d0)      = hi;
                    *(u16x4*)(dst + 32 + d0) = lo;
                }
            }
        }
    }
}

// ---------------------------------------------------------- K3: MFMA attention
// Grid 4096: block = (jh, i-quarter). 4 waves, each owns 16 q-rows. No LDS.
// Swapped QK^T: S^T[key][q] = mfma(K_tile, Q) so each lane holds the full
// 256-key score column for q = lane&15 (keys (lane>>4)*4 + r + 16*t).
__global__ __launch_bounds__(256) void attn_kernel(const u16* __restrict__ qt2,
                                                   const u16* __restrict__ kt2,
                                                   const u16* __restrict__ vth,
                                                   const u16* __restrict__ vtl,
                                                   const float* __restrict__ gb,
                                                   float* __restrict__ go)
{
    const int blk  = blockIdx.x;
    const int jh   = blk >> 2;
    const int q0   = (blk & 3) * 64 + (threadIdx.x >> 6) * 16;
    const int lane = threadIdx.x & 63;
    const int g    = lane >> 4;
    const int qc   = lane & 15;

    // Q B-fragments (col=q=lane&15, k-elems d=(lane>>4)*8..+8)
    const u16* qrow = qt2 + ((size_t)jh * 256 + q0 + qc) * 64;
    const short8 bqh = *(const short8*)(qrow + g * 8);
    const short8 bql = *(const short8*)(qrow + 32 + g * 8);

    f32x4 st[16];
    #pragma unroll
    for (int t = 0; t < 16; ++t) st[t] = (f32x4){0.f, 0.f, 0.f, 0.f};

    // QK^T: 16 key-tiles x 3 split terms
    const u16* kbase = kt2 + (size_t)jh * 256 * 64;
    #pragma unroll
    for (int kt = 0; kt < 16; ++kt) {
        const u16* krow = kbase + (size_t)(kt * 16 + qc) * 64;
        const short8 ah = *(const short8*)(krow + g * 8);
        const short8 al = *(const short8*)(krow + 32 + g * 8);
        st[kt] = __builtin_amdgcn_mfma_f32_16x16x32_bf16(ah, bqh, st[kt], 0, 0, 0);
        st[kt] = __builtin_amdgcn_mfma_f32_16x16x32_bf16(ah, bql, st[kt], 0, 0, 0);
        st[kt] = __builtin_amdgcn_mfma_f32_16x16x32_bf16(al, bqh, st[kt], 0, 0, 0);
    }

    // Softmax over all 256 keys for q = qc (64 local + cross-group reduce)
    float m = -1e30f;
    #pragma unroll
    for (int t = 0; t < 16; ++t)
        #pragma unroll
        for (int r = 0; r < 4; ++r) m = fmaxf(m, st[t][r]);
    m = fmaxf(m, __shfl_xor(m, 16));
    m = fmaxf(m, __shfl_xor(m, 32));

    float l = 0.0f;
    #pragma unroll
    for (int t = 0; t < 16; ++t)
        #pragma unroll
        for (int r = 0; r < 4; ++r) {
            const float p = __expf(st[t][r] - m);
            st[t][r] = p;
            l += p;
        }
    l += __shfl_xor(l, 16);
    l += __shfl_xor(l, 32);
    const float inv = 1.0f / l;
    #pragma unroll
    for (int t = 0; t < 16; ++t)
        #pragma unroll
        for (int r = 0; r < 4; ++r) st[t][r] *= inv;

    // PV: O[16q x 32d] = P @ V, P relayout via bpermute, split-bf16 x3
    f32x4 o0 = (f32x4){0.f, 0.f, 0.f, 0.f};
    f32x4 o1 = (f32x4){0.f, 0.f, 0.f, 0.f};
    const int slA   = qc + 16 * (2 * (g & 1));   // source lane, frag regs j<2
    const int slB   = slA + 16;                  // frag regs j>=2
    const bool upper = (g >> 1) != 0;            // target needs odd tile of pair
    const u16* vbh = vth + (size_t)jh * 32 * 256;
    const u16* vbl = vtl + (size_t)jh * 32 * 256;

    #pragma unroll
    for (int kc = 0; kc < 8; ++kc) {
        // pack p pairs (bf16 hi/lo) for tiles 2kc, 2kc+1
        u32 pkh[2][2], pkl[2][2];
        #pragma unroll
        for (int tt = 0; tt < 2; ++tt)
            #pragma unroll
            for (int u = 0; u < 2; ++u) {
                const float x = st[2 * kc + tt][2 * u];
                const float y = st[2 * kc + tt][2 * u + 1];
                const u16 hx = f2bf(x), hy = f2bf(y);
                pkh[tt][u] = (u32)hx | ((u32)hy << 16);
                const u16 lx = f2bf(x - bf2f(hx)), ly = f2bf(y - bf2f(hy));
                pkl[tt][u] = (u32)lx | ((u32)ly << 16);
            }
        // relayout to A-frag: lane needs keys kc*32+8g+2j,2j+1 for row q=qc
        u32x4 AH, AL;
        #pragma unroll
        for (int j = 0; j < 4; ++j) {
            const int u  = j & 1;
            const int sl = (j < 2) ? slA : slB;
            const u32 h0 = (u32)__shfl((int)pkh[0][u], sl);
            const u32 h1 = (u32)__shfl((int)pkh[1][u], sl);
            AH[j] = upper ? h1 : h0;
            const u32 l0 = (u32)__shfl((int)pkl[0][u], sl);
            const u32 l1 = (u32)__shfl((int)pkl[1][u], sl);
            AL[j] = upper ? l1 : l0;
        }
        const short8 pah = __builtin_bit_cast(short8, AH);
        const short8 pal = __builtin_bit_cast(short8, AL);
        // V B-frags (col=d=lane&15, k-elems keys (lane>>4)*8..+8)
        const size_t voff0 = (size_t)qc * 256 + kc * 32 + g * 8;          // d-tile 0
        const size_t voff1 = (size_t)(16 + qc) * 256 + kc * 32 + g * 8;   // d-tile 1
        const short8 b0h = *(const short8*)(vbh + voff0);
        const short8 b0l = *(const short8*)(vbl + voff0);
        const short8 b1h = *(const short8*)(vbh + voff1);
        const short8 b1l = *(const short8*)(vbl + voff1);
        o0 = __builtin_amdgcn_mfma_f32_16x16x32_bf16(pah, b0h, o0, 0, 0, 0);
        o0 = __builtin_amdgcn_mfma_f32_16x16x32_bf16(pah, b0l, o0, 0, 0, 0);
        o0 = __builtin_amdgcn_mfma_f32_16x16x32_bf16(pal, b0h, o0, 0, 0, 0);
        o1 = __builtin_amdgcn_mfma_f32_16x16x32_bf16(pah, b1h, o1, 0, 0, 0);
        o1 = __builtin_amdgcn_mfma_f32_16x16x32_bf16(pah, b1l, o1, 0, 0, 0);
        o1 = __builtin_amdgcn_mfma_f32_16x16x32_bf16(pal, b1h, o1, 0, 0, 0);
    }

    // Epilogue: gate and store. C/D rows = local q = g*4+r, col = d = qc(+16).
    const int jj = jh >> 2, h = jh & 3;
    #pragma unroll
    for (int r = 0; r < 4; ++r) {
        const int qg = q0 + g * 4 + r;
        const size_t base = ((size_t)qg * 256 + jj) * 128 + h * 32 + qc;
        go[base]      = gb[base]      * o0[r];
        go[base + 16] = gb[base + 16] * o1[r];
    }
}

// ------------------------------------------------------- K4: output GEMM
__global__ __launch_bounds__(256) void out_kernel(const float* __restrict__ A,
                                                  const float* __restrict__ W,
                                                  float* __restrict__ out)
{
    const int by   = blockIdx.x;
    const int row0 = by * 128;

    __shared__ float As[32][132];
    __shared__ float Bs[32][132];

    const int tid = threadIdx.x;
    const int tm  = tid & 15, tn = tid >> 4;
    const int m0  = tm * 4,  n0 = tn * 4;

    float acc[8][8];
    #pragma unroll
    for (int a = 0; a < 8; ++a)
        #pragma unroll
        for (int q = 0; q < 8; ++q) acc[a][q] = 0.0f;

    for (int kc = 0; kc < 128; kc += 32) {
        __syncthreads();
        #pragma unroll
        for (int it = 0; it < 4; ++it) {
            const int id = it * 256 + tid;
            const int m  = id >> 3;
            const int kq = (id & 7) * 4;
            const float4 a4 = *(const float4*)(A + (size_t)(row0 + m) * 128 + kc + kq);
            As[kq + 0][m] = a4.x; As[kq + 1][m] = a4.y;
            As[kq + 2][m] = a4.z; As[kq + 3][m] = a4.w;
        }
        #pragma unroll
        for (int it = 0; it < 4; ++it) {
            const int id = it * 256 + tid;
            const int kk = id >> 5;
            const int c4 = (id & 31) * 4;
            *(float4*)&Bs[kk][c4] = *(const float4*)(W + (size_t)(kc + kk) * 128 + c4);
        }
        __syncthreads();
        #pragma unroll
        for (int k = 0; k < 32; ++k) {
            const float4 a0 = *(const float4*)&As[k][m0];
            const float4 a1 = *(const float4*)&As[k][m0 + 64];
            const float4 b0 = *(const float4*)&Bs[k][n0];
            const float4 b1 = *(const float4*)&Bs[k][n0 + 64];
            const float av[8] = {a0.x, a0.y, a0.z, a0.w, a1.x, a1.y, a1.z, a1.w};
            const float bv[8] = {b0.x, b0.y, b0.z, b0.w, b1.x, b1.y, b1.z, b1.w};
            #pragma unroll
            for (int ii = 0; ii < 8; ++ii)
                #pragma unroll
                for (int jj = 0; jj < 8; ++jj)
                    acc[ii][jj] += av[ii] * bv[jj];
        }
    }

    #pragma unroll
    for (int ii = 0; ii < 8; ++ii) {
        const int mA = (ii < 4) ? (m0 + ii) : (m0 + 60 + ii);
        const int r  = row0 + mA;
        #pragma unroll
        for (int nh = 0; nh < 2; ++nh) {
            const int c0 = n0 + nh * 64;
            float4 vv;
            vv.x = acc[ii][nh * 4 + 0]; vv.y = acc[ii][nh * 4 + 1];
            vv.z = acc[ii][nh * 4 + 2]; vv.w = acc[ii][nh * 4 + 3];
            *(float4*)(out + (size_t)r * 128 + c0) = vv;
        }
    }
}

// ----------------------------------------------------------------- launch
extern "C" void kernel_launch(void* const* d_in, const int* in_sizes, int n_in,
                              void* d_out, int out_size, void* d_ws, size_t ws_size,
                              hipStream_t stream)
{
    const float* z   = (const float*)d_in[0];
    const float* lnw = (const float*)d_in[1];
    const float* lnb = (const float*)d_in[2];
    const float* wq  = (const float*)d_in[3];
    const float* wk  = (const float*)d_in[4];
    const float* wv  = (const float*)d_in[5];
    // d_in[6] = wb : unused (constant along softmax axis -> cancels)
    const float* wg  = (const float*)d_in[7];
    const float* wo  = (const float*)d_in[8];

    const size_t T = (size_t)NROWS * 128;       // 8,388,608 elements
    float* zn_go = (float*)d_ws;                // zn, later reused for g*o output
    float* gb    = zn_go + T;
    u16*   qt2   = (u16*)(gb + T);
    u16*   kt2   = qt2 + 2 * T;                 // 16.8M u16 each... (2*T u16 = 33.5MB)
    u16*   vth   = kt2 + 2 * T;
    u16*   vtl   = vth + T;
    // total: 2*4B*T + 2*(2*2B*T) + 2*(2B*T) = 167.8 MB

    ln_kernel  <<<16384,        256, 0, stream>>>(z, lnw, lnb, zn_go);
    proj_kernel<<<dim3(512, 4), 256, 0, stream>>>(zn_go, wq, wk, wv, wg, qt2, kt2, vth, vtl, gb);
    attn_kernel<<<4096,         256, 0, stream>>>(qt2, kt2, vth, vtl, gb, zn_go);
    out_kernel <<<512,          256, 0, stream>>>(zn_go, wo, (float*)d_out);
}

// Round 6
// 213.616 us; speedup vs baseline: 2.1069x; 1.3146x over previous
//
#include <hip/hip_runtime.h>

// TriangleAttentionStartingNode  (B=1, S=256, C=128, H=4, D=32)
//
// Pipeline:
//   K1 ln_kernel:   z (65536x128) -> zn (fp32)
//   K2 proj_kernel: zn @ {wq,wk,wv,wg} ->
//        qt2: split-bf16 [jh][i][32hi|32lo]   (scale 1/sqrt(D) folded into q)
//        kt2: split-bf16 [jh][k][32hi|32lo]
//        vth/vtl: split-bf16 transposed [jh][d=32][k=256]
//        gb:  fp32 sigmoid gate, row-major [i][j][128]
//   K3 attn_kernel: one block per (j,h); K/V staged once in swizzled LDS;
//        16 waves x 16 q-rows; swapped QK^T (split-bf16 x3), in-register
//        softmax, bpermute P->A-frag relayout (P-hi only), PV vs split V.
//   K4 out_kernel:  go @ wo -> d_out
//
// wb skipped: bias constant along softmax axis k -> cancels exactly.
//
// Round-5 bug fixed here: LDS staging used an 8-byte vector for 16-byte
// slots, leaving half of Ks/Vs uninitialized -> NaN. Staging now uses u16x8.

#define NROWS 65536   // S*S

typedef unsigned short u16;
typedef unsigned int   u32;
typedef __attribute__((ext_vector_type(8))) short short8;
typedef __attribute__((ext_vector_type(4))) float f32x4;
typedef __attribute__((ext_vector_type(4))) u32   u32x4;
typedef __attribute__((ext_vector_type(4))) u16   u16x4;
typedef __attribute__((ext_vector_type(8))) u16   u16x8;   // 16 B

__device__ __forceinline__ u16 f2bf(float x) {            // fp32 -> bf16 RNE
    u32 u = __builtin_bit_cast(u32, x);
    return (u16)((u + 0x7fffu + ((u >> 16) & 1u)) >> 16);
}
__device__ __forceinline__ float bf2f(u16 h) {
    u32 u = (u32)h << 16;
    return __builtin_bit_cast(float, u);
}

// ---------------------------------------------------------------- K1: LayerNorm
__global__ __launch_bounds__(256) void ln_kernel(const float* __restrict__ z,
                                                 const float* __restrict__ w,
                                                 const float* __restrict__ b,
                                                 float* __restrict__ zn)
{
    const int row  = blockIdx.x * 4 + (threadIdx.x >> 6);   // one wave per row
    const int lane = threadIdx.x & 63;
    const float2 v = *(const float2*)(z + (size_t)row * 128 + lane * 2);
    float s  = v.x + v.y;
    float ss = v.x * v.x + v.y * v.y;
    #pragma unroll
    for (int off = 32; off > 0; off >>= 1) {
        s  += __shfl_xor(s,  off);
        ss += __shfl_xor(ss, off);
    }
    const float mu  = s * (1.0f / 128.0f);
    const float var = ss * (1.0f / 128.0f) - mu * mu;
    const float rs  = rsqrtf(var + 1e-5f);
    const int c = lane * 2;
    float2 o;
    o.x = (v.x - mu) * rs * w[c]     + b[c];
    o.y = (v.y - mu) * rs * w[c + 1] + b[c + 1];
    *(float2*)(zn + (size_t)row * 128 + c) = o;
}

// ------------------------------------------------- K2: fused projection GEMM
__global__ __launch_bounds__(256) void proj_kernel(const float* __restrict__ zn,
                                                   const float* __restrict__ wq,
                                                   const float* __restrict__ wk,
                                                   const float* __restrict__ wv,
                                                   const float* __restrict__ wg,
                                                   u16* __restrict__ qt2,
                                                   u16* __restrict__ kt2,
                                                   u16* __restrict__ vth,
                                                   u16* __restrict__ vtl,
                                                   float* __restrict__ gb)
{
    const int by   = blockIdx.x;          // 0..511
    const int bx   = blockIdx.y;          // 0..3 : q,k,v,g
    const int row0 = by * 128;
    const float* __restrict__ W = (bx == 0) ? wq : (bx == 1) ? wk : (bx == 2) ? wv : wg;

    __shared__ float As[32][132];
    __shared__ float Bs[32][132];

    const int tid = threadIdx.x;
    const int tm  = tid & 15, tn = tid >> 4;
    const int m0  = tm * 4,  n0 = tn * 4;

    float acc[8][8];
    #pragma unroll
    for (int a = 0; a < 8; ++a)
        #pragma unroll
        for (int q = 0; q < 8; ++q) acc[a][q] = 0.0f;

    for (int kc = 0; kc < 128; kc += 32) {
        __syncthreads();
        #pragma unroll
        for (int it = 0; it < 4; ++it) {
            const int id = it * 256 + tid;
            const int m  = id >> 3;
            const int kq = (id & 7) * 4;
            const float4 a4 = *(const float4*)(zn + (size_t)(row0 + m) * 128 + kc + kq);
            As[kq + 0][m] = a4.x; As[kq + 1][m] = a4.y;
            As[kq + 2][m] = a4.z; As[kq + 3][m] = a4.w;
        }
        #pragma unroll
        for (int it = 0; it < 4; ++it) {
            const int id = it * 256 + tid;
            const int kk = id >> 5;
            const int c4 = (id & 31) * 4;
            *(float4*)&Bs[kk][c4] = *(const float4*)(W + (size_t)(kc + kk) * 128 + c4);
        }
        __syncthreads();
        #pragma unroll
        for (int k = 0; k < 32; ++k) {
            const float4 a0 = *(const float4*)&As[k][m0];
            const float4 a1 = *(const float4*)&As[k][m0 + 64];
            const float4 b0 = *(const float4*)&Bs[k][n0];
            const float4 b1 = *(const float4*)&Bs[k][n0 + 64];
            const float av[8] = {a0.x, a0.y, a0.z, a0.w, a1.x, a1.y, a1.z, a1.w};
            const float bv[8] = {b0.x, b0.y, b0.z, b0.w, b1.x, b1.y, b1.z, b1.w};
            #pragma unroll
            for (int ii = 0; ii < 8; ++ii)
                #pragma unroll
                for (int jj = 0; jj < 8; ++jj)
                    acc[ii][jj] += av[ii] * bv[jj];
        }
    }

    // Epilogue: split-bf16 scatter into attention layouts.
    #pragma unroll
    for (int ii = 0; ii < 8; ++ii) {
        const int mA = (ii < 4) ? (m0 + ii) : (m0 + 60 + ii);
        const int r  = row0 + mA;
        #pragma unroll
        for (int nh = 0; nh < 2; ++nh) {
            const int c0 = n0 + nh * 64;
            float vv[4] = {acc[ii][nh * 4 + 0], acc[ii][nh * 4 + 1],
                           acc[ii][nh * 4 + 2], acc[ii][nh * 4 + 3]};
            if (bx == 3) {
                float4 sg;
                sg.x = 1.0f / (1.0f + __expf(-vv[0]));
                sg.y = 1.0f / (1.0f + __expf(-vv[1]));
                sg.z = 1.0f / (1.0f + __expf(-vv[2]));
                sg.w = 1.0f / (1.0f + __expf(-vv[3]));
                *(float4*)(gb + (size_t)r * 128 + c0) = sg;
            } else {
                const int h  = c0 >> 5, d0 = c0 & 31;
                const int j  = (bx == 0) ? (r & 255) : (r >> 8);
                const int ot = (bx == 0) ? (r >> 8) : (r & 255);   // i or kk
                if (bx == 2) {
                    // V transposed: vth/vtl[(jh)*32 + d][kk]
                    #pragma unroll
                    for (int c = 0; c < 4; ++c) {
                        const float f = vv[c];
                        const u16 hx = f2bf(f);
                        const u16 lx = f2bf(f - bf2f(hx));
                        const size_t idx = ((size_t)(j * 4 + h) * 32 + d0 + c) * 256 + ot;
                        vth[idx] = hx; vtl[idx] = lx;
                    }
                } else {
                    u16* dst = ((bx == 0) ? qt2 : kt2) + ((size_t)(j * 4 + h) * 256 + ot) * 64;
                    const float sc = (bx == 0) ? 0.17677669529663687f : 1.0f; // 1/sqrt(32) into q
                    u16x4 hi, lo;
                    #pragma unroll
                    for (int c = 0; c < 4; ++c) {
                        const float f  = vv[c] * sc;
                        const u16  hx = f2bf(f);
                        hi[c] = hx;
                        lo[c] = f2bf(f - bf2f(hx));
                    }
                    *(u16x4*)(dst + d0)      = hi;
                    *(u16x4*)(dst + 32 + d0) = lo;
                }
            }
        }
    }
}

// ---------------------------------------------------------- K3: MFMA attention
// One block per jh (grid 1024), 1024 threads = 16 waves x 16 q-rows.
// K (split, [256][64] u16) and V (hi+lo, [32][256] u16 each) staged ONCE into
// LDS with XOR swizzle (16B slot ^= row&7) for conflict-reduced ds_read_b128.
// Swapped QK^T: lane (g,qc) holds score column q=qc, keys g*4+r+16t.
// PV uses P-hi only (bf16 round of normalized P in [0,1]).
__global__ __launch_bounds__(1024) void attn_kernel(const u16* __restrict__ qt2,
                                                    const u16* __restrict__ kt2,
                                                    const u16* __restrict__ vth,
                                                    const u16* __restrict__ vtl,
                                                    const float* __restrict__ gb,
                                                    float* __restrict__ go)
{
    const int jh   = blockIdx.x;
    const int tid  = threadIdx.x;
    const int q0   = (tid >> 6) * 16;          // wave id * 16
    const int lane = tid & 63;
    const int g    = lane >> 4;
    const int qc   = lane & 15;

    __shared__ u16 Ks[16384];    // 32 KB: [256 rows][8 slots x 8 u16], swizzled
    __shared__ u16 Vs[16384];    // 32 KB: vth [32][32 slots] then vtl, swizzled

    // ---- stage K/V into LDS (16B chunks, swizzle on write) ----
    {
        const u16* kg = kt2 + (size_t)jh * 16384;
        #pragma unroll
        for (int it = 0; it < 2; ++it) {
            const int t   = it * 1024 + tid;        // 2048 chunks of 8 u16
            const int row = t >> 3, c = t & 7;
            const int dc  = c ^ (row & 7);
            *(u16x8*)&Ks[row * 64 + dc * 8] = *(const u16x8*)(kg + t * 8);
        }
        const u16* vhg = vth + (size_t)jh * 8192;
        const u16* vlg = vtl + (size_t)jh * 8192;
        {
            const int t   = tid;                    // 1024 chunks
            const int row = t >> 5, c = t & 31;
            const int dc  = (c & 24) | ((c & 7) ^ (row & 7));
            *(u16x8*)&Vs[row * 256 + dc * 8] = *(const u16x8*)(vhg + t * 8);
        }
        {
            const int t   = tid;
            const int row = t >> 5, c = t & 31;
            const int dc  = (c & 24) | ((c & 7) ^ (row & 7));
            *(u16x8*)&Vs[8192 + row * 256 + dc * 8] = *(const u16x8*)(vlg + t * 8);
        }
    }

    // Q B-fragments from global (private per wave; coalesced)
    const u16* qrow = qt2 + ((size_t)jh * 256 + q0 + qc) * 64;
    const short8 bqh = *(const short8*)(qrow + g * 8);
    const short8 bql = *(const short8*)(qrow + 32 + g * 8);

    __syncthreads();

    // ---- QK^T: 16 key-tiles x 3 split terms, K from swizzled LDS ----
    f32x4 st[16];
    #pragma unroll
    for (int t = 0; t < 16; ++t) st[t] = (f32x4){0.f, 0.f, 0.f, 0.f};

    const int slotH = (g ^ (qc & 7)) * 8;        // u16 offset of hi slot
    #pragma unroll
    for (int kt = 0; kt < 16; ++kt) {
        const int rbase = (kt * 16 + qc) * 64;
        const short8 ah = *(const short8*)&Ks[rbase + slotH];
        const short8 al = *(const short8*)&Ks[rbase + (slotH ^ 32)];   // slot^4
        st[kt] = __builtin_amdgcn_mfma_f32_16x16x32_bf16(ah, bqh, st[kt], 0, 0, 0);
        st[kt] = __builtin_amdgcn_mfma_f32_16x16x32_bf16(ah, bql, st[kt], 0, 0, 0);
        st[kt] = __builtin_amdgcn_mfma_f32_16x16x32_bf16(al, bqh, st[kt], 0, 0, 0);
    }

    // ---- softmax over 256 keys for q = qc ----
    float m = -1e30f;
    #pragma unroll
    for (int t = 0; t < 16; ++t)
        #pragma unroll
        for (int r = 0; r < 4; ++r) m = fmaxf(m, st[t][r]);
    m = fmaxf(m, __shfl_xor(m, 16));
    m = fmaxf(m, __shfl_xor(m, 32));

    float l = 0.0f;
    #pragma unroll
    for (int t = 0; t < 16; ++t)
        #pragma unroll
        for (int r = 0; r < 4; ++r) {
            const float p = __expf(st[t][r] - m);
            st[t][r] = p;
            l += p;
        }
    l += __shfl_xor(l, 16);
    l += __shfl_xor(l, 32);
    const float inv = 1.0f / l;
    #pragma unroll
    for (int t = 0; t < 16; ++t)
        #pragma unroll
        for (int r = 0; r < 4; ++r) st[t][r] *= inv;

    // ---- PV: P-hi relayout via bpermute, V (hi+lo) from swizzled LDS ----
    f32x4 o0 = (f32x4){0.f, 0.f, 0.f, 0.f};
    f32x4 o1 = (f32x4){0.f, 0.f, 0.f, 0.f};
    const int  slA   = qc + 16 * (2 * (g & 1));
    const int  slB   = slA + 16;
    const bool upper = (g >> 1) != 0;

    #pragma unroll
    for (int kc = 0; kc < 8; ++kc) {
        u32 pkh[2][2];
        #pragma unroll
        for (int tt = 0; tt < 2; ++tt)
            #pragma unroll
            for (int u = 0; u < 2; ++u) {
                const float x = st[2 * kc + tt][2 * u];
                const float y = st[2 * kc + tt][2 * u + 1];
                pkh[tt][u] = (u32)f2bf(x) | ((u32)f2bf(y) << 16);
            }
        u32x4 AH;
        #pragma unroll
        for (int j = 0; j < 4; ++j) {
            const int u  = j & 1;
            const int sl = (j < 2) ? slA : slB;
            const u32 h0 = (u32)__shfl((int)pkh[0][u], sl);
            const u32 h1 = (u32)__shfl((int)pkh[1][u], sl);
            AH[j] = upper ? h1 : h0;
        }
        const short8 pah = __builtin_bit_cast(short8, AH);

        const int vc    = (((kc & 1) * 4 + g) ^ (qc & 7));
        const int vslot = ((kc >> 1) * 8 + vc) * 8;       // u16 offset in row
        const short8 b0h = *(const short8*)&Vs[        qc * 256 + vslot];
        const short8 b0l = *(const short8*)&Vs[8192 +  qc * 256 + vslot];
        const short8 b1h = *(const short8*)&Vs[       (16 + qc) * 256 + vslot];
        const short8 b1l = *(const short8*)&Vs[8192 + (16 + qc) * 256 + vslot];
        o0 = __builtin_amdgcn_mfma_f32_16x16x32_bf16(pah, b0h, o0, 0, 0, 0);
        o0 = __builtin_amdgcn_mfma_f32_16x16x32_bf16(pah, b0l, o0, 0, 0, 0);
        o1 = __builtin_amdgcn_mfma_f32_16x16x32_bf16(pah, b1h, o1, 0, 0, 0);
        o1 = __builtin_amdgcn_mfma_f32_16x16x32_bf16(pah, b1l, o1, 0, 0, 0);
    }

    // ---- epilogue: gate and store ----
    const int jj = jh >> 2, h = jh & 3;
    #pragma unroll
    for (int r = 0; r < 4; ++r) {
        const int qg = q0 + g * 4 + r;
        const size_t base = ((size_t)qg * 256 + jj) * 128 + h * 32 + qc;
        go[base]      = gb[base]      * o0[r];
        go[base + 16] = gb[base + 16] * o1[r];
    }
}

// ------------------------------------------------------- K4: output GEMM
__global__ __launch_bounds__(256) void out_kernel(const float* __restrict__ A,
                                                  const float* __restrict__ W,
                                                  float* __restrict__ out)
{
    const int by   = blockIdx.x;
    const int row0 = by * 128;

    __shared__ float As[32][132];
    __shared__ float Bs[32][132];

    const int tid = threadIdx.x;
    const int tm  = tid & 15, tn = tid >> 4;
    const int m0  = tm * 4,  n0 = tn * 4;

    float acc[8][8];
    #pragma unroll
    for (int a = 0; a < 8; ++a)
        #pragma unroll
        for (int q = 0; q < 8; ++q) acc[a][q] = 0.0f;

    for (int kc = 0; kc < 128; kc += 32) {
        __syncthreads();
        #pragma unroll
        for (int it = 0; it < 4; ++it) {
            const int id = it * 256 + tid;
            const int m  = id >> 3;
            const int kq = (id & 7) * 4;
            const float4 a4 = *(const float4*)(A + (size_t)(row0 + m) * 128 + kc + kq);
            As[kq + 0][m] = a4.x; As[kq + 1][m] = a4.y;
            As[kq + 2][m] = a4.z; As[kq + 3][m] = a4.w;
        }
        #pragma unroll
        for (int it = 0; it < 4; ++it) {
            const int id = it * 256 + tid;
            const int kk = id >> 5;
            const int c4 = (id & 31) * 4;
            *(float4*)&Bs[kk][c4] = *(const float4*)(W + (size_t)(kc + kk) * 128 + c4);
        }
        __syncthreads();
        #pragma unroll
        for (int k = 0; k < 32; ++k) {
            const float4 a0 = *(const float4*)&As[k][m0];
            const float4 a1 = *(const float4*)&As[k][m0 + 64];
            const float4 b0 = *(const float4*)&Bs[k][n0];
            const float4 b1 = *(const float4*)&Bs[k][n0 + 64];
            const float av[8] = {a0.x, a0.y, a0.z, a0.w, a1.x, a1.y, a1.z, a1.w};
            const float bv[8] = {b0.x, b0.y, b0.z, b0.w, b1.x, b1.y, b1.z, b1.w};
            #pragma unroll
            for (int ii = 0; ii < 8; ++ii)
                #pragma unroll
                for (int jj = 0; jj < 8; ++jj)
                    acc[ii][jj] += av[ii] * bv[jj];
        }
    }

    #pragma unroll
    for (int ii = 0; ii < 8; ++ii) {
        const int mA = (ii < 4) ? (m0 + ii) : (m0 + 60 + ii);
        const int r  = row0 + mA;
        #pragma unroll
        for (int nh = 0; nh < 2; ++nh) {
            const int c0 = n0 + nh * 64;
            float4 vv;
            vv.x = acc[ii][nh * 4 + 0]; vv.y = acc[ii][nh * 4 + 1];
            vv.z = acc[ii][nh * 4 + 2]; vv.w = acc[ii][nh * 4 + 3];
            *(float4*)(out + (size_t)r * 128 + c0) = vv;
        }
    }
}

// ----------------------------------------------------------------- launch
extern "C" void kernel_launch(void* const* d_in, const int* in_sizes, int n_in,
                              void* d_out, int out_size, void* d_ws, size_t ws_size,
                              hipStream_t stream)
{
    const float* z   = (const float*)d_in[0];
    const float* lnw = (const float*)d_in[1];
    const float* lnb = (const float*)d_in[2];
    const float* wq  = (const float*)d_in[3];
    const float* wk  = (const float*)d_in[4];
    const float* wv  = (const float*)d_in[5];
    // d_in[6] = wb : unused (constant along softmax axis -> cancels)
    const float* wg  = (const float*)d_in[7];
    const float* wo  = (const float*)d_in[8];

    const size_t T = (size_t)NROWS * 128;       // 8,388,608 elements
    float* zn_go = (float*)d_ws;                // zn, later reused for g*o output
    float* gb    = zn_go + T;
    u16*   qt2   = (u16*)(gb + T);
    u16*   kt2   = qt2 + 2 * T;
    u16*   vth   = kt2 + 2 * T;
    u16*   vtl   = vth + T;
    // total: 2*4B*T + 2*(2*2B*T) + 2*(2B*T) = 167.8 MB

    ln_kernel  <<<16384,        256, 0, stream>>>(z, lnw, lnb, zn_go);
    proj_kernel<<<dim3(512, 4), 256, 0, stream>>>(zn_go, wq, wk, wv, wg, qt2, kt2, vth, vtl, gb);
    attn_kernel<<<1024,        1024, 0, stream>>>(qt2, kt2, vth, vtl, gb, zn_go);
    out_kernel <<<512,          256, 0, stream>>>(zn_go, wo, (float*)d_out);
}

// Round 7
// 159.111 us; speedup vs baseline: 2.8286x; 1.3426x over previous
//
#include <hip/hip_runtime.h>

// TriangleAttentionStartingNode  (B=1, S=256, C=128, H=4, D=32)
//
// Pipeline:
//   K0 prep_w:  {wq,wk,wv,wg} -> wT split-bf16 [n=512][k=128] hi/lo (q-scale folded)
//   K1 lnproj:  z -> LN (fused, in-block) -> split-bf16 -> swizzled LDS ->
//               MFMA (A=W^T, B=zn^T, 3 split terms) -> epilogue scatter:
//                 qt2: [jh][i][32hi|32lo]  kt2: [jh][k][32hi|32lo]
//                 vth/vtl: [jh][d][k=256]  gb: fp32 sigmoid [row][128]
//   K2 attn:    one block per (j,h); K/V in swizzled LDS; 16 waves x 16 q-rows;
//               swapped QK^T (split x3), in-register softmax, bpermute P relayout
//               (P-hi only), PV vs split V; gated write -> go
//   K3 out:     go @ wo -> d_out (fp32 tile GEMM)
//
// wb skipped: bias constant along softmax axis k -> cancels exactly.

#define NROWS 65536   // S*S

typedef unsigned short u16;
typedef unsigned int   u32;
typedef __attribute__((ext_vector_type(8))) short short8;
typedef __attribute__((ext_vector_type(4))) float f32x4;
typedef __attribute__((ext_vector_type(4))) u32   u32x4;
typedef __attribute__((ext_vector_type(4))) u16   u16x4;
typedef __attribute__((ext_vector_type(8))) u16   u16x8;   // 16 B

__device__ __forceinline__ u16 f2bf(float x) {            // fp32 -> bf16 RNE
    u32 u = __builtin_bit_cast(u32, x);
    return (u16)((u + 0x7fffu + ((u >> 16) & 1u)) >> 16);
}
__device__ __forceinline__ float bf2f(u16 h) {
    u32 u = (u32)h << 16;
    return __builtin_bit_cast(float, u);
}

// ------------------------------------------------- K0: weight transpose+split
// wT[n][k] = W[k][n], n in [0,512) over {q|k|v|g}, split to bf16 hi/lo.
// Scale 1/sqrt(32) folded into wq.
__global__ __launch_bounds__(256) void prep_w(const float* __restrict__ wq,
                                              const float* __restrict__ wk,
                                              const float* __restrict__ wv,
                                              const float* __restrict__ wg,
                                              u16* __restrict__ wTh,
                                              u16* __restrict__ wTl)
{
    const int gid = blockIdx.x * 256 + threadIdx.x;   // 65536
    const int k = gid >> 9, n = gid & 511;
    const float* Wm = (n < 128) ? wq : (n < 256) ? wk : (n < 384) ? wv : wg;
    float f = Wm[k * 128 + (n & 127)];
    if (n < 128) f *= 0.17677669529663687f;           // 1/sqrt(D) into q
    const u16 h = f2bf(f);
    wTh[n * 128 + k] = h;
    wTl[n * 128 + k] = f2bf(f - bf2f(h));
}

// ------------------------------------------------- K1: fused LN + projection
// 512 blocks x 1024 threads (16 waves). Block owns 128 zn rows, all 512 outputs.
// LDS: LN'd rows as split-bf16, 16B slots XOR-swizzled (slot ^= row&15).
// MFMA swapped: A = W^T (global, L2-hot), B = zn^T (LDS). C'[n][m]: lane holds
// 4 consecutive n (output cols) for one m (zn row) -> vectorized epilogue.
__global__ __launch_bounds__(1024) void lnproj_kernel(const float* __restrict__ z,
                                                      const float* __restrict__ lnw,
                                                      const float* __restrict__ lnb,
                                                      const u16* __restrict__ wTh,
                                                      const u16* __restrict__ wTl,
                                                      u16* __restrict__ qt2,
                                                      u16* __restrict__ kt2,
                                                      u16* __restrict__ vth,
                                                      u16* __restrict__ vtl,
                                                      float* __restrict__ gb)
{
    const int row0 = blockIdx.x * 128;
    const int tid  = threadIdx.x;

    __shared__ u16 Ah[16384];   // 32 KB: [128 rows][16 slots of 8 u16], swizzled
    __shared__ u16 Al[16384];

    // ---- LN + split + stage (32 lanes per row, 4 iterations) ----
    {
        const int c4 = (tid & 31) * 4;                 // u16/float col, 0..124
        const float4 w4 = *(const float4*)(lnw + c4);
        const float4 b4 = *(const float4*)(lnb + c4);
        #pragma unroll
        for (int it = 0; it < 4; ++it) {
            const int row = it * 32 + (tid >> 5);
            const float4 v = *(const float4*)(z + (size_t)(row0 + row) * 128 + c4);
            float s  = v.x + v.y + v.z + v.w;
            float ss = v.x * v.x + v.y * v.y + v.z * v.z + v.w * v.w;
            #pragma unroll
            for (int off = 16; off > 0; off >>= 1) {
                s  += __shfl_xor(s,  off);
                ss += __shfl_xor(ss, off);
            }
            const float mu  = s * (1.0f / 128.0f);
            const float var = ss * (1.0f / 128.0f) - mu * mu;
            const float rs  = rsqrtf(var + 1e-5f);
            float o[4] = {(v.x - mu) * rs * w4.x + b4.x,
                          (v.y - mu) * rs * w4.y + b4.y,
                          (v.z - mu) * rs * w4.z + b4.z,
                          (v.w - mu) * rs * w4.w + b4.w};
            u16x4 hi, lo;
            #pragma unroll
            for (int c = 0; c < 4; ++c) {
                const u16 hx = f2bf(o[c]);
                hi[c] = hx;
                lo[c] = f2bf(o[c] - bf2f(hx));
            }
            const int slot = c4 >> 3, half = (c4 >> 2) & 1;
            const int phys = slot ^ (row & 15);
            *(u16x4*)&Ah[row * 128 + phys * 8 + half * 4] = hi;
            *(u16x4*)&Al[row * 128 + phys * 8 + half * 4] = lo;
        }
    }
    __syncthreads();

    // ---- MFMA: wave grid 8(n) x 2(m), wave tile 64x64 ----
    const int w    = tid >> 6;
    const int wn   = w >> 1, wm = w & 1;
    const int lane = tid & 63;
    const int g    = lane >> 4;
    const int qc   = lane & 15;

    f32x4 acc[4][4];   // [nt][mt]
    #pragma unroll
    for (int a = 0; a < 4; ++a)
        #pragma unroll
        for (int b = 0; b < 4; ++b) acc[a][b] = (f32x4){0.f, 0.f, 0.f, 0.f};

    #pragma unroll
    for (int kc = 0; kc < 4; ++kc) {
        // B-frags: zn^T from LDS (lane: col=m=row of zn, 8 k-elems)
        short8 bh[4], bl[4];
        #pragma unroll
        for (int mt = 0; mt < 4; ++mt) {
            const int row  = wm * 64 + mt * 16 + qc;
            const int phys = (kc * 4 + g) ^ (row & 15);
            bh[mt] = *(const short8*)&Ah[row * 128 + phys * 8];
            bl[mt] = *(const short8*)&Al[row * 128 + phys * 8];
        }
        #pragma unroll
        for (int nt = 0; nt < 4; ++nt) {
            const int n_row = wn * 64 + nt * 16 + qc;
            const short8 ah = *(const short8*)(wTh + (size_t)n_row * 128 + kc * 32 + g * 8);
            const short8 al = *(const short8*)(wTl + (size_t)n_row * 128 + kc * 32 + g * 8);
            #pragma unroll
            for (int mt = 0; mt < 4; ++mt) {
                acc[nt][mt] = __builtin_amdgcn_mfma_f32_16x16x32_bf16(ah, bh[mt], acc[nt][mt], 0, 0, 0);
                acc[nt][mt] = __builtin_amdgcn_mfma_f32_16x16x32_bf16(ah, bl[mt], acc[nt][mt], 0, 0, 0);
                acc[nt][mt] = __builtin_amdgcn_mfma_f32_16x16x32_bf16(al, bh[mt], acc[nt][mt], 0, 0, 0);
            }
        }
    }

    // ---- epilogue: lane holds 4 consecutive n for one m ----
    #pragma unroll
    for (int nt = 0; nt < 4; ++nt) {
        const int nb  = wn * 64 + nt * 16 + g * 4;     // first of 4 output cols
        const int mat = nb >> 7;                       // 0..3 : q,k,v,g (wave-uniform)
        const int nn  = nb & 127;
        #pragma unroll
        for (int mt = 0; mt < 4; ++mt) {
            const int m = row0 + wm * 64 + mt * 16 + qc;   // zn row
            const f32x4 a = acc[nt][mt];
            if (mat == 3) {
                float4 sg;
                sg.x = 1.0f / (1.0f + __expf(-a[0]));
                sg.y = 1.0f / (1.0f + __expf(-a[1]));
                sg.z = 1.0f / (1.0f + __expf(-a[2]));
                sg.w = 1.0f / (1.0f + __expf(-a[3]));
                *(float4*)(gb + (size_t)m * 128 + nn) = sg;
            } else {
                const int h = nn >> 5, d0 = nn & 31;
                if (mat == 2) {
                    const int j = m >> 8, kk = m & 255;
                    #pragma unroll
                    for (int r = 0; r < 4; ++r) {
                        const u16 hx = f2bf(a[r]);
                        const size_t idx = ((size_t)(j * 4 + h) * 32 + d0 + r) * 256 + kk;
                        vth[idx] = hx;
                        vtl[idx] = f2bf(a[r] - bf2f(hx));
                    }
                } else {
                    u16x4 hi, lo;
                    #pragma unroll
                    for (int c = 0; c < 4; ++c) {
                        const u16 hx = f2bf(a[c]);
                        hi[c] = hx;
                        lo[c] = f2bf(a[c] - bf2f(hx));
                    }
                    u16* dst;
                    if (mat == 0) {
                        const int i = m >> 8, j = m & 255;
                        dst = qt2 + ((size_t)(j * 4 + h) * 256 + i) * 64 + d0;
                    } else {
                        const int j = m >> 8, kk = m & 255;
                        dst = kt2 + ((size_t)(j * 4 + h) * 256 + kk) * 64 + d0;
                    }
                    *(u16x4*)dst        = hi;
                    *(u16x4*)(dst + 32) = lo;
                }
            }
        }
    }
}

// ---------------------------------------------------------- K2: MFMA attention
// One block per jh (grid 1024), 1024 threads = 16 waves x 16 q-rows.
// K (split, [256][64] u16) and V (hi+lo, [32][256] u16 each) staged ONCE into
// LDS with XOR swizzle (16B slot ^= row&7) for conflict-reduced ds_read_b128.
// Swapped QK^T: lane (g,qc) holds score column q=qc, keys g*4+r+16t.
// PV uses P-hi only (bf16 round of normalized P in [0,1]).
__global__ __launch_bounds__(1024) void attn_kernel(const u16* __restrict__ qt2,
                                                    const u16* __restrict__ kt2,
                                                    const u16* __restrict__ vth,
                                                    const u16* __restrict__ vtl,
                                                    const float* __restrict__ gb,
                                                    float* __restrict__ go)
{
    const int jh   = blockIdx.x;
    const int tid  = threadIdx.x;
    const int q0   = (tid >> 6) * 16;          // wave id * 16
    const int lane = tid & 63;
    const int g    = lane >> 4;
    const int qc   = lane & 15;

    __shared__ u16 Ks[16384];    // 32 KB: [256 rows][8 slots x 8 u16], swizzled
    __shared__ u16 Vs[16384];    // 32 KB: vth [32][32 slots] then vtl, swizzled

    // ---- stage K/V into LDS (16B chunks, swizzle on write) ----
    {
        const u16* kg = kt2 + (size_t)jh * 16384;
        #pragma unroll
        for (int it = 0; it < 2; ++it) {
            const int t   = it * 1024 + tid;        // 2048 chunks of 8 u16
            const int row = t >> 3, c = t & 7;
            const int dc  = c ^ (row & 7);
            *(u16x8*)&Ks[row * 64 + dc * 8] = *(const u16x8*)(kg + t * 8);
        }
        const u16* vhg = vth + (size_t)jh * 8192;
        const u16* vlg = vtl + (size_t)jh * 8192;
        {
            const int t   = tid;                    // 1024 chunks
            const int row = t >> 5, c = t & 31;
            const int dc  = (c & 24) | ((c & 7) ^ (row & 7));
            *(u16x8*)&Vs[row * 256 + dc * 8] = *(const u16x8*)(vhg + t * 8);
        }
        {
            const int t   = tid;
            const int row = t >> 5, c = t & 31;
            const int dc  = (c & 24) | ((c & 7) ^ (row & 7));
            *(u16x8*)&Vs[8192 + row * 256 + dc * 8] = *(const u16x8*)(vlg + t * 8);
        }
    }

    // Q B-fragments from global (private per wave; coalesced)
    const u16* qrow = qt2 + ((size_t)jh * 256 + q0 + qc) * 64;
    const short8 bqh = *(const short8*)(qrow + g * 8);
    const short8 bql = *(const short8*)(qrow + 32 + g * 8);

    __syncthreads();

    // ---- QK^T: 16 key-tiles x 3 split terms, K from swizzled LDS ----
    f32x4 st[16];
    #pragma unroll
    for (int t = 0; t < 16; ++t) st[t] = (f32x4){0.f, 0.f, 0.f, 0.f};

    const int slotH = (g ^ (qc & 7)) * 8;        // u16 offset of hi slot
    #pragma unroll
    for (int kt = 0; kt < 16; ++kt) {
        const int rbase = (kt * 16 + qc) * 64;
        const short8 ah = *(const short8*)&Ks[rbase + slotH];
        const short8 al = *(const short8*)&Ks[rbase + (slotH ^ 32)];   // slot^4
        st[kt] = __builtin_amdgcn_mfma_f32_16x16x32_bf16(ah, bqh, st[kt], 0, 0, 0);
        st[kt] = __builtin_amdgcn_mfma_f32_16x16x32_bf16(ah, bql, st[kt], 0, 0, 0);
        st[kt] = __builtin_amdgcn_mfma_f32_16x16x32_bf16(al, bqh, st[kt], 0, 0, 0);
    }

    // ---- softmax over 256 keys for q = qc ----
    float m = -1e30f;
    #pragma unroll
    for (int t = 0; t < 16; ++t)
        #pragma unroll
        for (int r = 0; r < 4; ++r) m = fmaxf(m, st[t][r]);
    m = fmaxf(m, __shfl_xor(m, 16));
    m = fmaxf(m, __shfl_xor(m, 32));

    float l = 0.0f;
    #pragma unroll
    for (int t = 0; t < 16; ++t)
        #pragma unroll
        for (int r = 0; r < 4; ++r) {
            const float p = __expf(st[t][r] - m);
            st[t][r] = p;
            l += p;
        }
    l += __shfl_xor(l, 16);
    l += __shfl_xor(l, 32);
    const float inv = 1.0f / l;
    #pragma unroll
    for (int t = 0; t < 16; ++t)
        #pragma unroll
        for (int r = 0; r < 4; ++r) st[t][r] *= inv;

    // ---- PV: P-hi relayout via bpermute, V (hi+lo) from swizzled LDS ----
    f32x4 o0 = (f32x4){0.f, 0.f, 0.f, 0.f};
    f32x4 o1 = (f32x4){0.f, 0.f, 0.f, 0.f};
    const int  slA   = qc + 16 * (2 * (g & 1));
    const int  slB   = slA + 16;
    const bool upper = (g >> 1) != 0;

    #pragma unroll
    for (int kc = 0; kc < 8; ++kc) {
        u32 pkh[2][2];
        #pragma unroll
        for (int tt = 0; tt < 2; ++tt)
            #pragma unroll
            for (int u = 0; u < 2; ++u) {
                const float x = st[2 * kc + tt][2 * u];
                const float y = st[2 * kc + tt][2 * u + 1];
                pkh[tt][u] = (u32)f2bf(x) | ((u32)f2bf(y) << 16);
            }
        u32x4 AH;
        #pragma unroll
        for (int j = 0; j < 4; ++j) {
            const int u  = j & 1;
            const int sl = (j < 2) ? slA : slB;
            const u32 h0 = (u32)__shfl((int)pkh[0][u], sl);
            const u32 h1 = (u32)__shfl((int)pkh[1][u], sl);
            AH[j] = upper ? h1 : h0;
        }
        const short8 pah = __builtin_bit_cast(short8, AH);

        const int vc    = (((kc & 1) * 4 + g) ^ (qc & 7));
        const int vslot = ((kc >> 1) * 8 + vc) * 8;       // u16 offset in row
        const short8 b0h = *(const short8*)&Vs[        qc * 256 + vslot];
        const short8 b0l = *(const short8*)&Vs[8192 +  qc * 256 + vslot];
        const short8 b1h = *(const short8*)&Vs[       (16 + qc) * 256 + vslot];
        const short8 b1l = *(const short8*)&Vs[8192 + (16 + qc) * 256 + vslot];
        o0 = __builtin_amdgcn_mfma_f32_16x16x32_bf16(pah, b0h, o0, 0, 0, 0);
        o0 = __builtin_amdgcn_mfma_f32_16x16x32_bf16(pah, b0l, o0, 0, 0, 0);
        o1 = __builtin_amdgcn_mfma_f32_16x16x32_bf16(pah, b1h, o1, 0, 0, 0);
        o1 = __builtin_amdgcn_mfma_f32_16x16x32_bf16(pah, b1l, o1, 0, 0, 0);
    }

    // ---- epilogue: gate and store ----
    const int jj = jh >> 2, h = jh & 3;
    #pragma unroll
    for (int r = 0; r < 4; ++r) {
        const int qg = q0 + g * 4 + r;
        const size_t base = ((size_t)qg * 256 + jj) * 128 + h * 32 + qc;
        go[base]      = gb[base]      * o0[r];
        go[base + 16] = gb[base + 16] * o1[r];
    }
}

// ------------------------------------------------------- K3: output GEMM
__global__ __launch_bounds__(256) void out_kernel(const float* __restrict__ A,
                                                  const float* __restrict__ W,
                                                  float* __restrict__ out)
{
    const int by   = blockIdx.x;
    const int row0 = by * 128;

    __shared__ float As[32][132];
    __shared__ float Bs[32][132];

    const int tid = threadIdx.x;
    const int tm  = tid & 15, tn = tid >> 4;
    const int m0  = tm * 4,  n0 = tn * 4;

    float acc[8][8];
    #pragma unroll
    for (int a = 0; a < 8; ++a)
        #pragma unroll
        for (int q = 0; q < 8; ++q) acc[a][q] = 0.0f;

    for (int kc = 0; kc < 128; kc += 32) {
        __syncthreads();
        #pragma unroll
        for (int it = 0; it < 4; ++it) {
            const int id = it * 256 + tid;
            const int m  = id >> 3;
            const int kq = (id & 7) * 4;
            const float4 a4 = *(const float4*)(A + (size_t)(row0 + m) * 128 + kc + kq);
            As[kq + 0][m] = a4.x; As[kq + 1][m] = a4.y;
            As[kq + 2][m] = a4.z; As[kq + 3][m] = a4.w;
        }
        #pragma unroll
        for (int it = 0; it < 4; ++it) {
            const int id = it * 256 + tid;
            const int kk = id >> 5;
            const int c4 = (id & 31) * 4;
            *(float4*)&Bs[kk][c4] = *(const float4*)(W + (size_t)(kc + kk) * 128 + c4);
        }
        __syncthreads();
        #pragma unroll
        for (int k = 0; k < 32; ++k) {
            const float4 a0 = *(const float4*)&As[k][m0];
            const float4 a1 = *(const float4*)&As[k][m0 + 64];
            const float4 b0 = *(const float4*)&Bs[k][n0];
            const float4 b1 = *(const float4*)&Bs[k][n0 + 64];
            const float av[8] = {a0.x, a0.y, a0.z, a0.w, a1.x, a1.y, a1.z, a1.w};
            const float bv[8] = {b0.x, b0.y, b0.z, b0.w, b1.x, b1.y, b1.z, b1.w};
            #pragma unroll
            for (int ii = 0; ii < 8; ++ii)
                #pragma unroll
                for (int jj = 0; jj < 8; ++jj)
                    acc[ii][jj] += av[ii] * bv[jj];
        }
    }

    #pragma unroll
    for (int ii = 0; ii < 8; ++ii) {
        const int mA = (ii < 4) ? (m0 + ii) : (m0 + 60 + ii);
        const int r  = row0 + mA;
        #pragma unroll
        for (int nh = 0; nh < 2; ++nh) {
            const int c0 = n0 + nh * 64;
            float4 vv;
            vv.x = acc[ii][nh * 4 + 0]; vv.y = acc[ii][nh * 4 + 1];
            vv.z = acc[ii][nh * 4 + 2]; vv.w = acc[ii][nh * 4 + 3];
            *(float4*)(out + (size_t)r * 128 + c0) = vv;
        }
    }
}

// ----------------------------------------------------------------- launch
extern "C" void kernel_launch(void* const* d_in, const int* in_sizes, int n_in,
                              void* d_out, int out_size, void* d_ws, size_t ws_size,
                              hipStream_t stream)
{
    const float* z   = (const float*)d_in[0];
    const float* lnw = (const float*)d_in[1];
    const float* lnb = (const float*)d_in[2];
    const float* wq  = (const float*)d_in[3];
    const float* wk  = (const float*)d_in[4];
    const float* wv  = (const float*)d_in[5];
    // d_in[6] = wb : unused (constant along softmax axis -> cancels)
    const float* wg  = (const float*)d_in[7];
    const float* wo  = (const float*)d_in[8];

    const size_t T = (size_t)NROWS * 128;       // 8,388,608 elements
    // ws slot 0 (33.5 MB): first hosts wT (256 KB, read by lnproj), then is
    // overwritten by attn's go output (stream-ordered, no overlap in liveness).
    float* go  = (float*)d_ws;
    u16*   wTh = (u16*)d_ws;
    u16*   wTl = wTh + 512 * 128;
    float* gb  = (float*)d_ws + T;
    u16*   qt2 = (u16*)(gb + T);
    u16*   kt2 = qt2 + 2 * T;
    u16*   vth = kt2 + 2 * T;
    u16*   vtl = vth + T;

    prep_w       <<<256,          256, 0, stream>>>(wq, wk, wv, wg, wTh, wTl);
    lnproj_kernel<<<512,         1024, 0, stream>>>(z, lnw, lnb, wTh, wTl,
                                                    qt2, kt2, vth, vtl, gb);
    attn_kernel  <<<1024,        1024, 0, stream>>>(qt2, kt2, vth, vtl, gb, go);
    out_kernel   <<<512,          256, 0, stream>>>(go, wo, (float*)d_out);
}